// Round 4
// baseline (1157.353 us; speedup 1.0000x reference)
//
#include <hip/hip_runtime.h>
#include <hip/hip_bf16.h>
#include <stdint.h>

// Fused gather + (ep-eq)^2 + MLP(256->256->256->1) for MI355X (gfx950).
//
// Round 4 changes vs round 3 (fused 236 us, Occ 32%, MfmaUtil 24%):
//  - PERSISTENT + SOFTWARE-PIPELINED: grid = 512 blocks (exactly 2/CU).
//    Each block loops over ~15 tiles; gather loads for tile t+1 are issued
//    BEFORE tile t's GEMMs (16 uint4/lane in VGPRs) and committed to the
//    other LDS buffer after GEMM2 -> L3 gather latency hidden under MFMA.
//  - Weights (both W1 and W2 wave-quarters) register-resident for the whole
//    kernel (64 short8/lane loaded once) -> K-loop is pure ds_read_b128+MFMA,
//    no per-tile L2 weight traffic (~2 GB saved).
//  - Double-buffered A/H LDS: 2 x 32 KB + 1 KB partials = 65.5 KB -> 2 blk/CU.
//  - launch_bounds(256,2): unified-file budget ~230 of 256 regs/wave.

#define D 256
#define MT 64
#define THREADS 256
#define PGRID 512

typedef __attribute__((ext_vector_type(8))) short short8;
typedef __attribute__((ext_vector_type(4))) float f32x4;

// bf16 round-to-nearest-even
__device__ __forceinline__ unsigned short f2bf(float f) {
    unsigned int u = __float_as_uint(f);
    unsigned int r = (u + 0x7FFFu + ((u >> 16) & 1u)) >> 16;
    return (unsigned short)r;
}
__device__ __forceinline__ float bflo(unsigned int u) { return __uint_as_float(u << 16); }
__device__ __forceinline__ float bfhi(unsigned int u) { return __uint_as_float(u & 0xFFFF0000u); }

__device__ __forceinline__ unsigned int sqdiff2(unsigned int p, unsigned int q) {
    float d0 = bflo(p) - bflo(q);
    float d1 = bfhi(p) - bfhi(q);
    return (unsigned int)f2bf(d0 * d0) | ((unsigned int)f2bf(d1 * d1) << 16);
}

// ---------------- embedding fp32 -> bf16 table ----------------
__global__ void conv_emb_kernel(const float* __restrict__ in,
                                unsigned short* __restrict__ out, int nchunks) {
    int i = blockIdx.x * blockDim.x + threadIdx.x;
    if (i >= nchunks) return;
    const float4* p = reinterpret_cast<const float4*>(in) + 2 * (size_t)i;
    float4 a = p[0], b = p[1];
    uint4 o;
    o.x = (unsigned int)f2bf(a.x) | ((unsigned int)f2bf(a.y) << 16);
    o.y = (unsigned int)f2bf(a.z) | ((unsigned int)f2bf(a.w) << 16);
    o.z = (unsigned int)f2bf(b.x) | ((unsigned int)f2bf(b.y) << 16);
    o.w = (unsigned int)f2bf(b.z) | ((unsigned int)f2bf(b.w) << 16);
    reinterpret_cast<uint4*>(out)[i] = o;
}

// ---------------- weight packing ----------------
// Pack W (row-major fp32 [K=256][N=256]) into bf16 B-fragments for
// v_mfma_f32_16x16x32_bf16. Fragment (nt, ks): lane L holds
//   B[k = ks*32 + (L>>4)*8 + j][n = nt*16 + (L&15)], j = 0..7
__global__ void pack_w_kernel(const float* __restrict__ w1,
                              const float* __restrict__ w2,
                              unsigned short* __restrict__ out) {
    int tid = blockIdx.x * blockDim.x + threadIdx.x;   // 0..16383
    int mat = tid >> 13;
    const float* W = mat ? w2 : w1;
    unsigned short* o = out + mat * 65536;
    int rem  = tid & 8191;
    int nt   = rem >> 9;
    int ks   = (rem >> 6) & 7;
    int lane = rem & 63;
    int kbase = ks * 32 + (lane >> 4) * 8;
    int n     = nt * 16 + (lane & 15);
    short8 v;
#pragma unroll
    for (int j = 0; j < 8; ++j)
        v[j] = (short)f2bf(W[(kbase + j) * 256 + n]);
    *reinterpret_cast<short8*>(o + (((nt * 8) + ks) * 64 + lane) * 8) = v;
}

// ---------------- fused main kernel (persistent, pipelined) ----------------
template <bool BF16T>
__launch_bounds__(THREADS, 2)
__global__ void fused_kernel(const int* __restrict__ pv,
                             const int* __restrict__ qv,
                             const float* __restrict__ embf,
                             const unsigned short* __restrict__ embb,
                             const float* __restrict__ b1,
                             const float* __restrict__ b2,
                             const float* __restrict__ w3,
                             const float* __restrict__ b3,
                             const unsigned short* __restrict__ wpack,
                             float* __restrict__ out,
                             int M, int nblk) {
    // two A/H tiles (GEMM1 reads A then overwrites in-place with H) + partials
    __shared__ unsigned char lds_a[2][MT * 512];
    __shared__ float lds_part[4][MT];

    const int tid  = threadIdx.x;
    const int lane = tid & 63;
    const int wave = tid >> 6;          // 0..3, n-quarter
    const int rr   = lane >> 5;         // half-wave row offset
    const int cc   = lane & 31;         // 16 B unit within row
    const int l15  = lane & 15;
    const int quad = lane >> 4;
    const int nbase = wave * 64;

    // ---- register-resident weights for this wave's 64-col quarter ----
    const short8* wp = reinterpret_cast<const short8*>(wpack);
    short8 wb1[4][8], wb2[4][8];
#pragma unroll
    for (int ct = 0; ct < 4; ++ct)
#pragma unroll
        for (int ks = 0; ks < 8; ++ks) {
            int fi = ((((nbase >> 4) + ct) * 8) + ks) * 64 + lane;
            wb1[ct][ks] = wp[fi];
            wb2[ct][ks] = wp[8192 + fi];
        }
    // biases / w3 per lane (column c = nbase + ct*16 + l15 is tile-invariant)
    float b1v[4], b2v[4], w3v[4];
#pragma unroll
    for (int ct = 0; ct < 4; ++ct) {
        int c = nbase + ct * 16 + l15;
        b1v[ct] = b1[c];
        b2v[ct] = b2[c];
        w3v[ct] = w3[c];
    }
    const float b3v = b3[0];

    auto issue_gather = [&](int t, uint4* ga, uint4* gb) {
#pragma unroll
        for (int it = 0; it < 8; ++it) {
            int r  = wave * 16 + it * 2 + rr;
            int gi = t * MT + r;
            int pi = 0, qi = 0;
            if (gi < M) { pi = pv[gi]; qi = qv[gi]; }
            ga[it] = *(reinterpret_cast<const uint4*>(embb + (size_t)pi * D) + cc);
            gb[it] = *(reinterpret_cast<const uint4*>(embb + (size_t)qi * D) + cc);
        }
    };
    auto commit_gather = [&](const uint4* ga, const uint4* gb, unsigned char* buf) {
#pragma unroll
        for (int it = 0; it < 8; ++it) {
            int r = wave * 16 + it * 2 + rr;
            uint4 o;
            o.x = sqdiff2(ga[it].x, gb[it].x);
            o.y = sqdiff2(ga[it].y, gb[it].y);
            o.z = sqdiff2(ga[it].z, gb[it].z);
            o.w = sqdiff2(ga[it].w, gb[it].w);
            unsigned int unit = (unsigned int)cc ^ (unsigned int)(r & 31);
            *reinterpret_cast<uint4*>(&buf[(unsigned int)r * 512u + (unit << 4)]) = o;
        }
    };
    auto gather_fp32 = [&](int t, unsigned char* buf) {
#pragma unroll
        for (int it = 0; it < 8; ++it) {
            int r  = wave * 16 + it * 2 + rr;
            int gi = t * MT + r;
            int pi = 0, qi = 0;
            if (gi < M) { pi = pv[gi]; qi = qv[gi]; }
            const float4* ep = reinterpret_cast<const float4*>(embf + (size_t)pi * D) + cc * 2;
            const float4* eq = reinterpret_cast<const float4*>(embf + (size_t)qi * D) + cc * 2;
            float4 a0 = ep[0], a1 = ep[1], q0 = eq[0], q1 = eq[1];
            float d0 = a0.x - q0.x, d1 = a0.y - q0.y, d2 = a0.z - q0.z, d3 = a0.w - q0.w;
            float d4 = a1.x - q1.x, d5 = a1.y - q1.y, d6 = a1.z - q1.z, d7 = a1.w - q1.w;
            uint4 o;
            o.x = (unsigned int)f2bf(d0 * d0) | ((unsigned int)f2bf(d1 * d1) << 16);
            o.y = (unsigned int)f2bf(d2 * d2) | ((unsigned int)f2bf(d3 * d3) << 16);
            o.z = (unsigned int)f2bf(d4 * d4) | ((unsigned int)f2bf(d5 * d5) << 16);
            o.w = (unsigned int)f2bf(d6 * d6) | ((unsigned int)f2bf(d7 * d7) << 16);
            unsigned int unit = (unsigned int)cc ^ (unsigned int)(r & 31);
            *reinterpret_cast<uint4*>(&buf[(unsigned int)r * 512u + (unit << 4)]) = o;
        }
    };
    // K-loop: A from LDS, B from registers (no global traffic, no barriers)
    auto gemm = [&](const short8 (&wbg)[4][8], const unsigned char* buf,
                    f32x4 (&acc)[4][4]) {
#pragma unroll
        for (int mt = 0; mt < 4; ++mt)
#pragma unroll
            for (int ct = 0; ct < 4; ++ct)
                acc[mt][ct] = (f32x4){0.f, 0.f, 0.f, 0.f};
#pragma unroll
        for (int ks = 0; ks < 8; ++ks) {
            short8 af[4];
#pragma unroll
            for (int mt = 0; mt < 4; ++mt) {
                int r = mt * 16 + l15;
                unsigned int unit = (unsigned int)(ks * 4 + quad) ^ (unsigned int)(r & 31);
                af[mt] = *reinterpret_cast<const short8*>(
                    &buf[(unsigned int)r * 512u + (unit << 4)]);
            }
#pragma unroll
            for (int mt = 0; mt < 4; ++mt)
#pragma unroll
                for (int ct = 0; ct < 4; ++ct)
                    acc[mt][ct] = __builtin_amdgcn_mfma_f32_16x16x32_bf16(
                        af[mt], wbg[ct][ks], acc[mt][ct], 0, 0, 0);
        }
    };

    const int stride = gridDim.x;
    int t = blockIdx.x;
    if (t >= nblk) return;              // whole block exits together

    uint4 ga[8], gb[8];
    int cur = 0;

    // prologue: fill buf 0 with tile t
    if (BF16T) { issue_gather(t, ga, gb); commit_gather(ga, gb, lds_a[0]); }
    else       { gather_fp32(t, lds_a[0]); }
    __syncthreads();

    for (; t < nblk; t += stride) {
        const int  tn = t + stride;
        const bool hn = (tn < nblk);

        // (a) issue next tile's gathers early; they fly under the GEMMs
        if (BF16T && hn) issue_gather(tn, ga, gb);

        f32x4 acc[4][4];
        // (b) GEMM1
        gemm(wb1, lds_a[cur], acc);
        __syncthreads();                              // B1: all A reads done

        // (c) epilogue1: +b1, relu, bf16 -> same buffer as H
#pragma unroll
        for (int ct = 0; ct < 4; ++ct) {
            int c = nbase + ct * 16 + l15;
#pragma unroll
            for (int mt = 0; mt < 4; ++mt)
#pragma unroll
                for (int j = 0; j < 4; ++j) {
                    float v = fmaxf(acc[mt][ct][j] + b1v[ct], 0.f);
                    int r = mt * 16 + quad * 4 + j;
                    unsigned int unit = (unsigned int)(c >> 3) ^ (unsigned int)(r & 31);
                    unsigned int addr = (unsigned int)r * 512u + (unit << 4)
                                      + (unsigned int)(c & 7) * 2u;
                    *reinterpret_cast<unsigned short*>(&lds_a[cur][addr]) = f2bf(v);
                }
        }
        __syncthreads();                              // B2: H visible

        // (d) GEMM2 + fused w3 dot
        gemm(wb2, lds_a[cur], acc);

        float part[4][4];
#pragma unroll
        for (int mt = 0; mt < 4; ++mt)
#pragma unroll
            for (int j = 0; j < 4; ++j)
                part[mt][j] = 0.f;
#pragma unroll
        for (int ct = 0; ct < 4; ++ct)
#pragma unroll
            for (int mt = 0; mt < 4; ++mt)
#pragma unroll
                for (int j = 0; j < 4; ++j) {
                    float v = fmaxf(acc[mt][ct][j] + b2v[ct], 0.f);
                    part[mt][j] += v * w3v[ct];
                }
#pragma unroll
        for (int msk = 8; msk >= 1; msk >>= 1)
#pragma unroll
            for (int mt = 0; mt < 4; ++mt)
#pragma unroll
                for (int j = 0; j < 4; ++j)
                    part[mt][j] += __shfl_xor(part[mt][j], msk, 64);
        if (l15 == 0) {
#pragma unroll
            for (int mt = 0; mt < 4; ++mt)
#pragma unroll
                for (int j = 0; j < 4; ++j)
                    lds_part[wave][mt * 16 + quad * 4 + j] = part[mt][j];
        }

        // (e) commit next tile into the other buffer (loads arrived long ago)
        if (hn) {
            if (BF16T) commit_gather(ga, gb, lds_a[cur ^ 1]);
            else       gather_fp32(tn, lds_a[cur ^ 1]);
        }
        __syncthreads();                              // B3: partials + next A

        // (f) out store for tile t
        if (tid < MT) {
            int gi = t * MT + tid;
            if (gi < M) {
                out[gi] = lds_part[0][tid] + lds_part[1][tid] +
                          lds_part[2][tid] + lds_part[3][tid] + b3v;
            }
        }
        cur ^= 1;
    }
}

extern "C" void kernel_launch(void* const* d_in, const int* in_sizes, int n_in,
                              void* d_out, int out_size, void* d_ws, size_t ws_size,
                              hipStream_t stream) {
    const int*   pv  = (const int*)d_in[0];
    const int*   qv  = (const int*)d_in[1];
    const float* emb = (const float*)d_in[2];
    const float* w1  = (const float*)d_in[3];
    const float* b1  = (const float*)d_in[4];
    const float* w2  = (const float*)d_in[5];
    const float* b2  = (const float*)d_in[6];
    const float* w3  = (const float*)d_in[7];
    const float* b3  = (const float*)d_in[8];
    float* out = (float*)d_out;
    const int M  = in_sizes[0];
    const int NV = in_sizes[2] / D;

    const size_t tbl_bytes   = (size_t)NV * D * sizeof(unsigned short); // 102.4 MB
    const size_t wpack_bytes = 2u * 65536u * sizeof(unsigned short);    // 256 KB
    const bool use_bf16 = (ws_size >= tbl_bytes + wpack_bytes);         // launch-constant

    unsigned short* table = (unsigned short*)d_ws;
    unsigned short* wpack = use_bf16
        ? (unsigned short*)((char*)d_ws + tbl_bytes)
        : (unsigned short*)d_ws;

    pack_w_kernel<<<32, 512, 0, stream>>>(w1, w2, wpack);

    const int nblk = (M + MT - 1) / MT;
    const int grid = nblk < PGRID ? nblk : PGRID;
    if (use_bf16) {
        int nch = (int)((size_t)NV * D / 8);
        conv_emb_kernel<<<(nch + 255) / 256, 256, 0, stream>>>(emb, table, nch);
        fused_kernel<true><<<grid, THREADS, 0, stream>>>(
            pv, qv, emb, table, b1, b2, w3, b3, wpack, out, M, nblk);
    } else {
        fused_kernel<false><<<grid, THREADS, 0, stream>>>(
            pv, qv, emb, nullptr, b1, b2, w3, b3, wpack, out, M, nblk);
    }
}